// Round 11
// baseline (405.745 us; speedup 1.0000x reference)
//
#include <hip/hip_runtime.h>
#include <hip/hip_fp16.h>

typedef float f2v __attribute__((ext_vector_type(2)));
typedef float f4v __attribute__((ext_vector_type(4)));
typedef int   i2v __attribute__((ext_vector_type(2)));

// 24B packed row: 10 x f16 (20B) + 4B pad, 8B-aligned. As table = 2.4MB.
struct __attribute__((packed, aligned(8))) Row24 {
    uint2 ab;   // h0..h3
    uint2 cd;   // h4..h7
    uint  e;    // h8..h9
    uint  pad;
};

__device__ __forceinline__ float2 h2f2(uint v) {
    __half2 h = *(__half2*)&v;
    return __half22float2(h);
}

// ---- prep: A_s[n] = x_s[n] @ W1[0:10,:]  -> f16 Row24 (2.4 MB) ----
__global__ __launch_bounds__(256) void prep_as(const float* __restrict__ xs,
                                               const float* __restrict__ W1,
                                               Row24* __restrict__ As, int N) {
    const int n = blockIdx.x * 256 + threadIdx.x;
    if (n >= N) return;
    float f[10];
    const float2* p = (const float2*)(xs + (size_t)n * 10);
    #pragma unroll
    for (int i = 0; i < 5; ++i) { float2 v = p[i]; f[2 * i] = v.x; f[2 * i + 1] = v.y; }
    float a[10];
    #pragma unroll
    for (int j = 0; j < 10; ++j) a[j] = 0.f;
    #pragma unroll
    for (int k = 0; k < 10; ++k) {
        const float fk = f[k];
        #pragma unroll
        for (int j = 0; j < 10; ++j) a[j] += fk * W1[k * 10 + j];   // uniform -> s_load
    }
    uint q[5];
    #pragma unroll
    for (int i = 0; i < 5; ++i) {
        __half2 h = __floats2half2_rn(a[2 * i], a[2 * i + 1]);
        q[i] = *(uint*)&h;
    }
    Row24 r;
    r.ab = make_uint2(q[0], q[1]);
    r.cd = make_uint2(q[2], q[3]);
    r.e  = q[4];
    r.pad = 0;
    As[n] = r;
}

// ---- prep: x_t[n] -> 5 x f16 packed into 16B (one dwordx4 gather; 1.6 MB) ----
__global__ __launch_bounds__(256) void prep_xt(const float* __restrict__ xt,
                                               uint4* __restrict__ Xt, int N) {
    const int n = blockIdx.x * 256 + threadIdx.x;
    if (n >= N) return;
    float f[5];
    #pragma unroll
    for (int i = 0; i < 5; ++i) f[i] = xt[(size_t)n * 5 + i];
    __half2 h01 = __floats2half2_rn(f[0], f[1]);
    __half2 h23 = __floats2half2_rn(f[2], f[3]);
    __half2 h4_ = __floats2half2_rn(f[4], 0.f);
    uint4 r;
    r.x = *(uint*)&h01;
    r.y = *(uint*)&h23;
    r.z = *(uint*)&h4_;
    r.w = 0;
    Xt[n] = r;
}

// shared per-edge MLP tail (forceinline; all indices compile-time)
__device__ __forceinline__ void mlp_edge(const float* __restrict__ g,   // 10 ea values
                                         Row24 ra, uint4 rt, int ib,
                                         const float* __restrict__ sUp,
                                         const float* __restrict__ W1,
                                         const float* __restrict__ W2,
                                         const float* __restrict__ b2,
                                         float* __restrict__ o)        // 10 outputs
{
    float h[10];
    {
        uint qa[5] = { ra.ab.x, ra.ab.y, ra.cd.x, ra.cd.y, ra.e };
        #pragma unroll
        for (int i = 0; i < 5; ++i) {
            float2 a2 = h2f2(qa[i]);
            h[2 * i]     = a2.x + sUp[ib * 12 + 2 * i];
            h[2 * i + 1] = a2.y + sUp[ib * 12 + 2 * i + 1];
        }
    }
    {
        float2 t01 = h2f2(rt.x), t23 = h2f2(rt.y), t4_ = h2f2(rt.z);
        const float tv[5] = { t01.x, t01.y, t23.x, t23.y, t4_.x };
        #pragma unroll
        for (int k = 0; k < 5; ++k) {
            const float fk = tv[k];
            #pragma unroll
            for (int j = 0; j < 10; ++j) h[j] += fk * W1[(10 + k) * 10 + j];
        }
    }
    #pragma unroll
    for (int k = 0; k < 10; ++k) {
        const float gk = g[k];
        #pragma unroll
        for (int j = 0; j < 10; ++j) h[j] += gk * W1[(15 + k) * 10 + j];
    }
    #pragma unroll
    for (int j = 0; j < 10; ++j) h[j] = (h[j] >= 0.f) ? h[j] : 0.1f * h[j];

    #pragma unroll
    for (int j = 0; j < 10; ++j) o[j] = b2[j];
    #pragma unroll
    for (int k = 0; k < 10; ++k) {
        const float hk = h[k];
        #pragma unroll
        for (int j = 0; j < 10; ++j) o[j] += hk * W2[k * 10 + j];
    }
}

// ---- main: one EDGE PAIR per thread; ea/out moved as aligned 16B vectors ----
__global__ __launch_bounds__(256)
__attribute__((amdgpu_waves_per_eu(4, 4)))
void edge_mlp_pair(
    const Row24* __restrict__ As,
    const uint4* __restrict__ Xt,
    const int* __restrict__ src,
    const int* __restrict__ tgt,
    const float* __restrict__ ea,
    const float* __restrict__ u,
    const int* __restrict__ be,
    const float* __restrict__ W1,
    const float* __restrict__ b1,
    const float* __restrict__ W2,
    const float* __restrict__ b2,
    float* __restrict__ out, int E)
{
    __shared__ float sUp[16 * 12];    // U' = u @ W1[25:35] + b1

    const int t = threadIdx.x;
    if (t < 160) {
        const int b = t / 10, j = t % 10;
        float acc = b1[j];
        #pragma unroll
        for (int k = 0; k < 10; ++k) acc += u[b * 10 + k] * W1[(25 + k) * 10 + j];
        sUp[b * 12 + j] = acc;
    }
    __syncthreads();

    const long long p  = (long long)blockIdx.x * 256 + t;   // pair index
    const long long e0 = 2 * p;
    const long long e1 = e0 + 1;
    if (e0 >= E) return;

    if (e1 < E) {
        // ---- fast path: full pair ----
        const i2v s2  = __builtin_nontemporal_load((const i2v*)src + p);
        const i2v t2  = __builtin_nontemporal_load((const i2v*)tgt + p);
        const i2v ib2 = __builtin_nontemporal_load((const i2v*)be + p);

        Row24 ra0 = As[s2[0]];
        Row24 ra1 = As[s2[1]];
        uint4 rt0 = Xt[t2[0]];
        uint4 rt1 = Xt[t2[1]];

        // ea pair: 80B, 16B-aligned -> 5 x dwordx4 NT
        const f4v* pe = (const f4v*)(ea + e0 * 10);
        f4v A0 = __builtin_nontemporal_load(pe + 0);
        f4v A1 = __builtin_nontemporal_load(pe + 1);
        f4v A2 = __builtin_nontemporal_load(pe + 2);
        f4v A3 = __builtin_nontemporal_load(pe + 3);
        f4v A4 = __builtin_nontemporal_load(pe + 4);

        const float g0[10] = { A0[0], A0[1], A0[2], A0[3], A1[0], A1[1], A1[2], A1[3], A2[0], A2[1] };
        const float g1[10] = { A2[2], A2[3], A3[0], A3[1], A3[2], A3[3], A4[0], A4[1], A4[2], A4[3] };

        float o0[10], o1[10];
        mlp_edge(g0, ra0, rt0, ib2[0], sUp, W1, W2, b2, o0);   // sequential: o0 done
        mlp_edge(g1, ra1, rt1, ib2[1], sUp, W1, W2, b2, o1);   // before o1 starts

        // out pair: 5 x dwordx4 temporal (write-combining proven at 125MB)
        f4v* po = (f4v*)(out + e0 * 10);
        f4v S0 = { o0[0], o0[1], o0[2], o0[3] };
        f4v S1 = { o0[4], o0[5], o0[6], o0[7] };
        f4v S2 = { o0[8], o0[9], o1[0], o1[1] };
        f4v S3 = { o1[2], o1[3], o1[4], o1[5] };
        f4v S4 = { o1[6], o1[7], o1[8], o1[9] };
        po[0] = S0; po[1] = S1; po[2] = S2; po[3] = S3; po[4] = S4;
    } else {
        // ---- tail: single edge (only if E is odd) ----
        const int is = src[e0], it = tgt[e0], ib = be[e0];
        Row24 ra = As[is];
        uint4 rt = Xt[it];
        float g[10];
        const f2v* pe = (const f2v*)(ea + e0 * 10);
        #pragma unroll
        for (int i = 0; i < 5; ++i) {
            f2v v = pe[i];
            g[2 * i] = v[0]; g[2 * i + 1] = v[1];
        }
        float o[10];
        mlp_edge(g, ra, rt, ib, sUp, W1, W2, b2, o);
        float2* po = (float2*)(out + e0 * 10);
        #pragma unroll
        for (int i = 0; i < 5; ++i) { float2 v; v.x = o[2 * i]; v.y = o[2 * i + 1]; po[i] = v; }
    }
}

// ---- fallback (ws too small): direct compute from raw tables ----
__global__ __launch_bounds__(256) void edge_mlp_raw(
    const float* __restrict__ xs, const float* __restrict__ xt,
    const int* __restrict__ src, const int* __restrict__ tgt,
    const float* __restrict__ ea, const float* __restrict__ u,
    const int* __restrict__ be,
    const float* __restrict__ W1, const float* __restrict__ b1,
    const float* __restrict__ W2, const float* __restrict__ b2,
    float* __restrict__ out, int E)
{
    __shared__ float sUp[16 * 12];
    const int t = threadIdx.x;
    if (t < 160) {
        const int b = t / 10, j = t % 10;
        float acc = b1[j];
        #pragma unroll
        for (int k = 0; k < 10; ++k) acc += u[b * 10 + k] * W1[(25 + k) * 10 + j];
        sUp[b * 12 + j] = acc;
    }
    __syncthreads();
    const int e = blockIdx.x * 256 + t;
    if (e >= E) return;
    const int is = src[e], it = tgt[e], ib = be[e];
    float f[25];
    const float* ps = xs + (size_t)is * 10;
    #pragma unroll
    for (int i = 0; i < 5; ++i) {
        float2 v = *(const float2*)(ps + 2 * i);
        f[2 * i] = v.x; f[2 * i + 1] = v.y;
    }
    const float* pt = xt + (size_t)it * 5;
    #pragma unroll
    for (int i = 0; i < 5; ++i) f[10 + i] = pt[i];
    const float2* pe = (const float2*)(ea + (size_t)e * 10);
    #pragma unroll
    for (int i = 0; i < 5; ++i) { float2 v = pe[i]; f[15 + 2 * i] = v.x; f[16 + 2 * i] = v.y; }
    float h[10];
    #pragma unroll
    for (int j = 0; j < 10; ++j) h[j] = sUp[ib * 12 + j];
    #pragma unroll
    for (int k = 0; k < 25; ++k) {
        const float fk = f[k];
        #pragma unroll
        for (int j = 0; j < 10; ++j) h[j] += fk * W1[k * 10 + j];
    }
    #pragma unroll
    for (int j = 0; j < 10; ++j) h[j] = (h[j] >= 0.f) ? h[j] : 0.1f * h[j];
    float o[10];
    #pragma unroll
    for (int j = 0; j < 10; ++j) o[j] = b2[j];
    #pragma unroll
    for (int k = 0; k < 10; ++k) {
        const float hk = h[k];
        #pragma unroll
        for (int j = 0; j < 10; ++j) o[j] += hk * W2[k * 10 + j];
    }
    float2* po = (float2*)(out + (size_t)e * 10);
    #pragma unroll
    for (int i = 0; i < 5; ++i) { float2 v; v.x = o[2 * i]; v.y = o[2 * i + 1]; po[i] = v; }
}

extern "C" void kernel_launch(void* const* d_in, const int* in_sizes, int n_in,
                              void* d_out, int out_size, void* d_ws, size_t ws_size,
                              hipStream_t stream) {
    const float* x_s      = (const float*)d_in[0];
    const float* x_t      = (const float*)d_in[1];
    const int*   ei       = (const int*)d_in[2];    // (2, E) flat: [src | tgt]
    const float* edge_att = (const float*)d_in[3];
    const float* u        = (const float*)d_in[4];
    const int*   batch_e  = (const int*)d_in[5];
    const float* W1       = (const float*)d_in[6];
    const float* b1       = (const float*)d_in[7];
    const float* W2       = (const float*)d_in[8];
    const float* b2       = (const float*)d_in[9];
    float* out = (float*)d_out;

    const int E   = in_sizes[5];
    const int N_S = in_sizes[0] / 10;
    const int N_T = in_sizes[1] / 5;

    const size_t need = (size_t)N_S * sizeof(Row24) + (size_t)N_T * sizeof(uint4);
    if (ws_size >= need) {
        Row24* As = (Row24*)d_ws;
        uint4* Xt = (uint4*)((char*)d_ws + (size_t)N_S * sizeof(Row24));
        prep_as<<<(N_S + 255) / 256, 256, 0, stream>>>(x_s, W1, As, N_S);
        prep_xt<<<(N_T + 255) / 256, 256, 0, stream>>>(x_t, Xt, N_T);
        const long long npairs = ((long long)E + 1) / 2;
        const int blocks = (int)((npairs + 255) / 256);
        edge_mlp_pair<<<blocks, 256, 0, stream>>>(
            As, Xt, ei, ei + E, edge_att, u, batch_e,
            W1, b1, W2, b2, out, E);
    } else {
        const int blocks = (E + 255) / 256;
        edge_mlp_raw<<<blocks, 256, 0, stream>>>(
            x_s, x_t, ei, ei + E, edge_att, u, batch_e,
            W1, b1, W2, b2, out, E);
    }
}

// Round 12
// 104.686 us; speedup vs baseline: 3.8758x; 3.8758x over previous
//
#include <hip/hip_runtime.h>
#include <hip/hip_fp16.h>

typedef float f2v __attribute__((ext_vector_type(2)));
typedef float f4v __attribute__((ext_vector_type(4)));

// 24B packed row: 10 x f16 (20B) + 4B pad, 8B-aligned. As table = 2.4MB.
struct __attribute__((packed, aligned(8))) Row24 {
    uint2 ab;   // h0..h3
    uint2 cd;   // h4..h7
    uint  e;    // h8..h9
    uint  pad;
};

__device__ __forceinline__ float2 h2f2(uint v) {
    __half2 h = *(__half2*)&v;
    return __half22float2(h);
}

// ---- prep: A_s[n] = x_s[n] @ W1[0:10,:]  -> f16 Row24 (2.4 MB) ----
__global__ __launch_bounds__(256) void prep_as(const float* __restrict__ xs,
                                               const float* __restrict__ W1,
                                               Row24* __restrict__ As, int N) {
    const int n = blockIdx.x * 256 + threadIdx.x;
    if (n >= N) return;
    float f[10];
    const float2* p = (const float2*)(xs + (size_t)n * 10);
    #pragma unroll
    for (int i = 0; i < 5; ++i) { float2 v = p[i]; f[2 * i] = v.x; f[2 * i + 1] = v.y; }
    float a[10];
    #pragma unroll
    for (int j = 0; j < 10; ++j) a[j] = 0.f;
    #pragma unroll
    for (int k = 0; k < 10; ++k) {
        const float fk = f[k];
        #pragma unroll
        for (int j = 0; j < 10; ++j) a[j] += fk * W1[k * 10 + j];   // uniform -> s_load
    }
    uint q[5];
    #pragma unroll
    for (int i = 0; i < 5; ++i) {
        __half2 h = __floats2half2_rn(a[2 * i], a[2 * i + 1]);
        q[i] = *(uint*)&h;
    }
    Row24 r;
    r.ab = make_uint2(q[0], q[1]);
    r.cd = make_uint2(q[2], q[3]);
    r.e  = q[4];
    r.pad = 0;
    As[n] = r;
}

// ---- prep: x_t[n] -> 5 x f16 packed into 16B (one dwordx4 gather; 1.6 MB) ----
__global__ __launch_bounds__(256) void prep_xt(const float* __restrict__ xt,
                                               uint4* __restrict__ Xt, int N) {
    const int n = blockIdx.x * 256 + threadIdx.x;
    if (n >= N) return;
    float f[5];
    #pragma unroll
    for (int i = 0; i < 5; ++i) f[i] = xt[(size_t)n * 5 + i];
    __half2 h01 = __floats2half2_rn(f[0], f[1]);
    __half2 h23 = __floats2half2_rn(f[2], f[3]);
    __half2 h4_ = __floats2half2_rn(f[4], 0.f);
    uint4 r;
    r.x = *(uint*)&h01;
    r.y = *(uint*)&h23;
    r.z = *(uint*)&h4_;
    r.w = 0;
    Xt[n] = r;
}

// shared per-edge MLP tail (forceinline; all indices compile-time)
__device__ __forceinline__ void mlp_edge(const float* __restrict__ g,   // 10 ea values
                                         Row24 ra, uint4 rt, int ib,
                                         const float* __restrict__ sUp,
                                         const float* __restrict__ W1,
                                         const float* __restrict__ W2,
                                         const float* __restrict__ b2,
                                         float* __restrict__ o)        // 10 outputs
{
    float h[10];
    {
        uint qa[5] = { ra.ab.x, ra.ab.y, ra.cd.x, ra.cd.y, ra.e };
        #pragma unroll
        for (int i = 0; i < 5; ++i) {
            float2 a2 = h2f2(qa[i]);
            h[2 * i]     = a2.x + sUp[ib * 12 + 2 * i];
            h[2 * i + 1] = a2.y + sUp[ib * 12 + 2 * i + 1];
        }
    }
    {
        float2 t01 = h2f2(rt.x), t23 = h2f2(rt.y), t4_ = h2f2(rt.z);
        const float tv[5] = { t01.x, t01.y, t23.x, t23.y, t4_.x };
        #pragma unroll
        for (int k = 0; k < 5; ++k) {
            const float fk = tv[k];
            #pragma unroll
            for (int j = 0; j < 10; ++j) h[j] += fk * W1[(10 + k) * 10 + j];
        }
    }
    #pragma unroll
    for (int k = 0; k < 10; ++k) {
        const float gk = g[k];
        #pragma unroll
        for (int j = 0; j < 10; ++j) h[j] += gk * W1[(15 + k) * 10 + j];
    }
    #pragma unroll
    for (int j = 0; j < 10; ++j) h[j] = (h[j] >= 0.f) ? h[j] : 0.1f * h[j];

    #pragma unroll
    for (int j = 0; j < 10; ++j) o[j] = b2[j];
    #pragma unroll
    for (int k = 0; k < 10; ++k) {
        const float hk = h[k];
        #pragma unroll
        for (int j = 0; j < 10; ++j) o[j] += hk * W2[k * 10 + j];
    }
}

// ---- main: one edge/thread (r8 registers) + LDS-staged ea/out (r9 transactions) ----
__global__ __launch_bounds__(256) void edge_mlp_stage(
    const Row24* __restrict__ As,
    const uint4* __restrict__ Xt,
    const int* __restrict__ src,
    const int* __restrict__ tgt,
    const float* __restrict__ ea,
    const float* __restrict__ u,
    const int* __restrict__ be,
    const float* __restrict__ W1,
    const float* __restrict__ b1,
    const float* __restrict__ W2,
    const float* __restrict__ b2,
    float* __restrict__ out, int E)
{
    __shared__ float sUp[16 * 12];    // U' = u @ W1[25:35] + b1
    __shared__ float stage[2560];     // 256 edges x 10 floats: ea in, out later

    const int t = threadIdx.x;
    if (t < 160) {
        const int b = t / 10, j = t % 10;
        float acc = b1[j];
        #pragma unroll
        for (int k = 0; k < 10; ++k) acc += u[b * 10 + k] * W1[(25 + k) * 10 + j];
        sUp[b * 12 + j] = acc;
    }

    const int  base_e = blockIdx.x * 256;
    const long long base_f = (long long)base_e * 10;
    const bool full = (base_e + 256) <= E;

    // ---- stage-in ea: 640 NT dwordx4 per block (40 lines/wave vs 320 strided) ----
    if (full) {
        const f4v* pe = (const f4v*)(ea + base_f);
        #pragma unroll
        for (int r = 0; r < 3; ++r) {
            int i = t + r * 256;
            if (i < 640) ((f4v*)stage)[i] = __builtin_nontemporal_load(pe + i);
        }
    } else {
        const long long totalf = (long long)E * 10;
        for (int i = t; i < 2560; i += 256)
            if (base_f + i < totalf) stage[i] = ea[base_f + i];
    }
    __syncthreads();

    const int e = base_e + t;
    float o[10];
    bool valid = e < E;
    if (valid) {
        // idx: NT scalar loads (streams stay out of L2)
        const int is = __builtin_nontemporal_load(src + e);
        const int it = __builtin_nontemporal_load(tgt + e);
        const int ib = __builtin_nontemporal_load(be + e);

        Row24 ra = As[is];            // dwordx4 + dwordx2, L2-resident table
        uint4 rt = Xt[it];            // dwordx4, L2-resident table

        float g[10];
        const f2v* pg = (const f2v*)&stage[t * 10];   // t*40B is 8B-aligned
        #pragma unroll
        for (int i = 0; i < 5; ++i) { f2v v = pg[i]; g[2 * i] = v[0]; g[2 * i + 1] = v[1]; }

        mlp_edge(g, ra, rt, ib, sUp, W1, W2, b2, o);
    }

    if (full) {
        // own-row write (no cross-thread hazard), then cooperative dwordx4 store
        __syncthreads();   // all ea reads done before stage reuse (paranoia: own-row only, but cheap)
        #pragma unroll
        for (int i = 0; i < 5; ++i) {
            f2v v; v[0] = o[2 * i]; v[1] = o[2 * i + 1];
            *(f2v*)&stage[t * 10 + 2 * i] = v;
        }
        __syncthreads();
        f4v* po = (f4v*)(out + base_f);
        #pragma unroll
        for (int r = 0; r < 3; ++r) {
            int i = t + r * 256;
            if (i < 640) po[i] = ((const f4v*)stage)[i];
        }
    } else if (valid) {
        float2* po = (float2*)(out + (size_t)e * 10);
        #pragma unroll
        for (int i = 0; i < 5; ++i) { float2 v; v.x = o[2 * i]; v.y = o[2 * i + 1]; po[i] = v; }
    }
}

// ---- fallback (ws too small): direct compute from raw tables ----
__global__ __launch_bounds__(256) void edge_mlp_raw(
    const float* __restrict__ xs, const float* __restrict__ xt,
    const int* __restrict__ src, const int* __restrict__ tgt,
    const float* __restrict__ ea, const float* __restrict__ u,
    const int* __restrict__ be,
    const float* __restrict__ W1, const float* __restrict__ b1,
    const float* __restrict__ W2, const float* __restrict__ b2,
    float* __restrict__ out, int E)
{
    __shared__ float sUp[16 * 12];
    const int t = threadIdx.x;
    if (t < 160) {
        const int b = t / 10, j = t % 10;
        float acc = b1[j];
        #pragma unroll
        for (int k = 0; k < 10; ++k) acc += u[b * 10 + k] * W1[(25 + k) * 10 + j];
        sUp[b * 12 + j] = acc;
    }
    __syncthreads();
    const int e = blockIdx.x * 256 + t;
    if (e >= E) return;
    const int is = src[e], it = tgt[e], ib = be[e];
    float f[25];
    const float* ps = xs + (size_t)is * 10;
    #pragma unroll
    for (int i = 0; i < 5; ++i) {
        float2 v = *(const float2*)(ps + 2 * i);
        f[2 * i] = v.x; f[2 * i + 1] = v.y;
    }
    const float* pt = xt + (size_t)it * 5;
    #pragma unroll
    for (int i = 0; i < 5; ++i) f[10 + i] = pt[i];
    const float2* pe = (const float2*)(ea + (size_t)e * 10);
    #pragma unroll
    for (int i = 0; i < 5; ++i) { float2 v = pe[i]; f[15 + 2 * i] = v.x; f[16 + 2 * i] = v.y; }
    float h[10];
    #pragma unroll
    for (int j = 0; j < 10; ++j) h[j] = sUp[ib * 12 + j];
    #pragma unroll
    for (int k = 0; k < 25; ++k) {
        const float fk = f[k];
        #pragma unroll
        for (int j = 0; j < 10; ++j) h[j] += fk * W1[k * 10 + j];
    }
    #pragma unroll
    for (int j = 0; j < 10; ++j) h[j] = (h[j] >= 0.f) ? h[j] : 0.1f * h[j];
    float o[10];
    #pragma unroll
    for (int j = 0; j < 10; ++j) o[j] = b2[j];
    #pragma unroll
    for (int k = 0; k < 10; ++k) {
        const float hk = h[k];
        #pragma unroll
        for (int j = 0; j < 10; ++j) o[j] += hk * W2[k * 10 + j];
    }
    float2* po = (float2*)(out + (size_t)e * 10);
    #pragma unroll
    for (int i = 0; i < 5; ++i) { float2 v; v.x = o[2 * i]; v.y = o[2 * i + 1]; po[i] = v; }
}

extern "C" void kernel_launch(void* const* d_in, const int* in_sizes, int n_in,
                              void* d_out, int out_size, void* d_ws, size_t ws_size,
                              hipStream_t stream) {
    const float* x_s      = (const float*)d_in[0];
    const float* x_t      = (const float*)d_in[1];
    const int*   ei       = (const int*)d_in[2];    // (2, E) flat: [src | tgt]
    const float* edge_att = (const float*)d_in[3];
    const float* u        = (const float*)d_in[4];
    const int*   batch_e  = (const int*)d_in[5];
    const float* W1       = (const float*)d_in[6];
    const float* b1       = (const float*)d_in[7];
    const float* W2       = (const float*)d_in[8];
    const float* b2       = (const float*)d_in[9];
    float* out = (float*)d_out;

    const int E   = in_sizes[5];
    const int N_S = in_sizes[0] / 10;
    const int N_T = in_sizes[1] / 5;
    const int blocks = (E + 255) / 256;

    const size_t need = (size_t)N_S * sizeof(Row24) + (size_t)N_T * sizeof(uint4);
    if (ws_size >= need) {
        Row24* As = (Row24*)d_ws;
        uint4* Xt = (uint4*)((char*)d_ws + (size_t)N_S * sizeof(Row24));
        prep_as<<<(N_S + 255) / 256, 256, 0, stream>>>(x_s, W1, As, N_S);
        prep_xt<<<(N_T + 255) / 256, 256, 0, stream>>>(x_t, Xt, N_T);
        edge_mlp_stage<<<blocks, 256, 0, stream>>>(
            As, Xt, ei, ei + E, edge_att, u, batch_e,
            W1, b1, W2, b2, out, E);
    } else {
        edge_mlp_raw<<<blocks, 256, 0, stream>>>(
            x_s, x_t, ei, ei + E, edge_att, u, batch_e,
            W1, b1, W2, b2, out, E);
    }
}

// Round 13
// 102.444 us; speedup vs baseline: 3.9606x; 1.0219x over previous
//
#include <hip/hip_runtime.h>
#include <hip/hip_fp16.h>

typedef float f2v __attribute__((ext_vector_type(2)));
typedef float f4v __attribute__((ext_vector_type(4)));

#define LDS_AS __attribute__((address_space(3)))
#define GLB_AS __attribute__((address_space(1)))

// 24B packed row: 10 x f16 (20B) + 4B pad, 8B-aligned. As table = 2.4MB.
struct __attribute__((packed, aligned(8))) Row24 {
    uint2 ab;   // h0..h3
    uint2 cd;   // h4..h7
    uint  e;    // h8..h9
    uint  pad;
};

__device__ __forceinline__ float2 h2f2(uint v) {
    __half2 h = *(__half2*)&v;
    return __half22float2(h);
}

// ---- prep: A_s[n] = x_s[n] @ W1[0:10,:]  -> f16 Row24 (2.4 MB) ----
__global__ __launch_bounds__(256) void prep_as(const float* __restrict__ xs,
                                               const float* __restrict__ W1,
                                               Row24* __restrict__ As, int N) {
    const int n = blockIdx.x * 256 + threadIdx.x;
    if (n >= N) return;
    float f[10];
    const float2* p = (const float2*)(xs + (size_t)n * 10);
    #pragma unroll
    for (int i = 0; i < 5; ++i) { float2 v = p[i]; f[2 * i] = v.x; f[2 * i + 1] = v.y; }
    float a[10];
    #pragma unroll
    for (int j = 0; j < 10; ++j) a[j] = 0.f;
    #pragma unroll
    for (int k = 0; k < 10; ++k) {
        const float fk = f[k];
        #pragma unroll
        for (int j = 0; j < 10; ++j) a[j] += fk * W1[k * 10 + j];   // uniform -> s_load
    }
    uint q[5];
    #pragma unroll
    for (int i = 0; i < 5; ++i) {
        __half2 h = __floats2half2_rn(a[2 * i], a[2 * i + 1]);
        q[i] = *(uint*)&h;
    }
    Row24 r;
    r.ab = make_uint2(q[0], q[1]);
    r.cd = make_uint2(q[2], q[3]);
    r.e  = q[4];
    r.pad = 0;
    As[n] = r;
}

// ---- prep: x_t[n] -> 5 x f16 packed into 16B (one dwordx4 gather; 1.6 MB) ----
__global__ __launch_bounds__(256) void prep_xt(const float* __restrict__ xt,
                                               uint4* __restrict__ Xt, int N) {
    const int n = blockIdx.x * 256 + threadIdx.x;
    if (n >= N) return;
    float f[5];
    #pragma unroll
    for (int i = 0; i < 5; ++i) f[i] = xt[(size_t)n * 5 + i];
    __half2 h01 = __floats2half2_rn(f[0], f[1]);
    __half2 h23 = __floats2half2_rn(f[2], f[3]);
    __half2 h4_ = __floats2half2_rn(f[4], 0.f);
    uint4 r;
    r.x = *(uint*)&h01;
    r.y = *(uint*)&h23;
    r.z = *(uint*)&h4_;
    r.w = 0;
    Xt[n] = r;
}

// shared per-edge MLP tail (forceinline; all indices compile-time)
__device__ __forceinline__ void mlp_edge(const float* __restrict__ g,   // 10 ea values
                                         Row24 ra, uint4 rt, int ib,
                                         const float* __restrict__ sUp,
                                         const float* __restrict__ W1,
                                         const float* __restrict__ W2,
                                         const float* __restrict__ b2,
                                         float* __restrict__ o)        // 10 outputs
{
    float h[10];
    {
        uint qa[5] = { ra.ab.x, ra.ab.y, ra.cd.x, ra.cd.y, ra.e };
        #pragma unroll
        for (int i = 0; i < 5; ++i) {
            float2 a2 = h2f2(qa[i]);
            h[2 * i]     = a2.x + sUp[ib * 12 + 2 * i];
            h[2 * i + 1] = a2.y + sUp[ib * 12 + 2 * i + 1];
        }
    }
    {
        float2 t01 = h2f2(rt.x), t23 = h2f2(rt.y), t4_ = h2f2(rt.z);
        const float tv[5] = { t01.x, t01.y, t23.x, t23.y, t4_.x };
        #pragma unroll
        for (int k = 0; k < 5; ++k) {
            const float fk = tv[k];
            #pragma unroll
            for (int j = 0; j < 10; ++j) h[j] += fk * W1[(10 + k) * 10 + j];
        }
    }
    #pragma unroll
    for (int k = 0; k < 10; ++k) {
        const float gk = g[k];
        #pragma unroll
        for (int j = 0; j < 10; ++j) h[j] += gk * W1[(15 + k) * 10 + j];
    }
    #pragma unroll
    for (int j = 0; j < 10; ++j) h[j] = (h[j] >= 0.f) ? h[j] : 0.1f * h[j];

    #pragma unroll
    for (int j = 0; j < 10; ++j) o[j] = b2[j];
    #pragma unroll
    for (int k = 0; k < 10; ++k) {
        const float hk = h[k];
        #pragma unroll
        for (int j = 0; j < 10; ++j) o[j] += hk * W2[k * 10 + j];
    }
}

// ---- main: persistent blocks, double-buffered LDS ea-stage via global_load_lds ----
__global__ __launch_bounds__(256) void edge_mlp_dbuf(
    const Row24* __restrict__ As,
    const uint4* __restrict__ Xt,
    const int* __restrict__ src,
    const int* __restrict__ tgt,
    const float* __restrict__ ea,
    const float* __restrict__ u,
    const int* __restrict__ be,
    const float* __restrict__ W1,
    const float* __restrict__ b1,
    const float* __restrict__ W2,
    const float* __restrict__ b2,
    float* __restrict__ out, int E, int ntiles)
{
    __shared__ float sUp[16 * 12];                 // U' = u @ W1[25:35] + b1
    __shared__ __align__(16) float stage[2][2560]; // double-buffered 256x10 tile

    const int t = threadIdx.x;
    if (t < 160) {
        const int b = t / 10, j = t % 10;
        float acc = b1[j];
        #pragma unroll
        for (int k = 0; k < 10; ++k) acc += u[b * 10 + k] * W1[(25 + k) * 10 + j];
        sUp[b * 12 + j] = acc;
    }

    int tile = blockIdx.x;
    const int tstride = gridDim.x;
    if (tile >= ntiles) return;   // whole block exits before any barrier

    const int wave_base4 = (t & ~63) * 4;   // wave-uniform LDS float offset base

    // ---- stage tile tl into buf (async direct-to-LDS for full tiles) ----
    auto stage_tile = [&](int tl, int buf) {
        const int base_e = tl * 256;
        if (base_e + 256 <= E) {
            const float* gsrc = ea + (size_t)base_e * 10;
            {   // chunk 0: elements [0,256)
                const float* g0 = gsrc + (size_t)t * 4;
                float* l0 = &stage[buf][wave_base4];
                __builtin_amdgcn_global_load_lds((const GLB_AS uint*)g0, (LDS_AS uint*)l0, 16, 0, 0);
            }
            {   // chunk 1: elements [256,512)
                const float* g1 = gsrc + (size_t)(256 + t) * 4;
                float* l1 = &stage[buf][1024 + wave_base4];
                __builtin_amdgcn_global_load_lds((const GLB_AS uint*)g1, (LDS_AS uint*)l1, 16, 0, 0);
            }
            if (t < 128) {   // chunk 2: elements [512,640) — waves 0,1 only (wave-uniform)
                const float* g2 = gsrc + (size_t)(512 + t) * 4;
                float* l2 = &stage[buf][2048 + wave_base4];
                __builtin_amdgcn_global_load_lds((const GLB_AS uint*)g2, (LDS_AS uint*)l2, 16, 0, 0);
            }
        } else {
            const long long base_f = (long long)base_e * 10;
            const long long totalf = (long long)E * 10;
            for (int i = t; i < 2560; i += 256)
                if (base_f + i < totalf) stage[buf][i] = ea[base_f + i];
        }
    };
    auto load_idx = [&](int tl, int& is, int& it, int& ib) {
        long long e = (long long)tl * 256 + t;
        long long c = (e < E) ? e : (long long)(E - 1);
        is = __builtin_nontemporal_load(src + c);
        it = __builtin_nontemporal_load(tgt + c);
        ib = __builtin_nontemporal_load(be + c);
    };

    // ---- prologue ----
    int cur = 0;
    stage_tile(tile, 0);
    int is0, it0, ib0;
    load_idx(tile, is0, it0, ib0);
    __syncthreads();   // drains stage(tile0) + idx + sUp visible

    for (;;) {
        const int ntile = tile + tstride;
        const bool have_next = ntile < ntiles;

        int is1, it1, ib1;
        if (have_next) {
            stage_tile(ntile, cur ^ 1);        // async; hides under compute below
            load_idx(ntile, is1, it1, ib1);    // NT; consumed next iteration
        }

        // ---- compute current tile ----
        const int base_e = tile * 256;
        const int e = base_e + t;
        const bool full = (base_e + 256) <= E;
        const bool valid = e < E;
        float o[10];
        if (valid) {
            Row24 ra = As[is0];   // L2-resident table gathers
            uint4 rt = Xt[it0];
            float g[10];
            const f2v* pg = (const f2v*)&stage[cur][t * 10];
            #pragma unroll
            for (int i = 0; i < 5; ++i) { f2v v = pg[i]; g[2 * i] = v[0]; g[2 * i + 1] = v[1]; }
            mlp_edge(g, ra, rt, ib0, sUp, W1, W2, b2, o);
        }

        if (full) {
            // own-row write back into the same buffer (no cross-thread hazard)
            #pragma unroll
            for (int i = 0; i < 5; ++i) {
                f2v v; v[0] = o[2 * i]; v[1] = o[2 * i + 1];
                *(f2v*)&stage[cur][t * 10 + 2 * i] = v;
            }
            __syncthreads();   // o-rows visible; also drains stage(ntile) for next iter
            // cooperative dwordx4 store of the whole tile
            const f4v* sp = (const f4v*)stage[cur];
            f4v* po = (f4v*)(out + (size_t)base_e * 10);
            po[t] = sp[t];
            po[t + 256] = sp[t + 256];
            if (t < 128) po[t + 512] = sp[t + 512];
        } else {
            __syncthreads();   // uniform barrier count within block
            if (valid) {
                float2* po = (float2*)(out + (size_t)e * 10);
                #pragma unroll
                for (int i = 0; i < 5; ++i) { float2 v; v.x = o[2 * i]; v.y = o[2 * i + 1]; po[i] = v; }
            }
        }

        if (!have_next) break;

        // end barrier: coop-store LDS reads (already lgkm-waited via data dep) must
        // complete block-wide before next iteration stages into stage[cur].
        // Raw s_barrier: do NOT drain vmcnt (don't wait on store acks / next-stage loads).
        __builtin_amdgcn_sched_barrier(0);
        __builtin_amdgcn_s_barrier();
        __builtin_amdgcn_sched_barrier(0);

        tile = ntile; cur ^= 1;
        is0 = is1; it0 = it1; ib0 = ib1;
    }
}

// ---- fallback (ws too small): direct compute from raw tables ----
__global__ __launch_bounds__(256) void edge_mlp_raw(
    const float* __restrict__ xs, const float* __restrict__ xt,
    const int* __restrict__ src, const int* __restrict__ tgt,
    const float* __restrict__ ea, const float* __restrict__ u,
    const int* __restrict__ be,
    const float* __restrict__ W1, const float* __restrict__ b1,
    const float* __restrict__ W2, const float* __restrict__ b2,
    float* __restrict__ out, int E)
{
    __shared__ float sUp[16 * 12];
    const int t = threadIdx.x;
    if (t < 160) {
        const int b = t / 10, j = t % 10;
        float acc = b1[j];
        #pragma unroll
        for (int k = 0; k < 10; ++k) acc += u[b * 10 + k] * W1[(25 + k) * 10 + j];
        sUp[b * 12 + j] = acc;
    }
    __syncthreads();
    const int e = blockIdx.x * 256 + t;
    if (e >= E) return;
    const int is = src[e], it = tgt[e], ib = be[e];
    float f[25];
    const float* ps = xs + (size_t)is * 10;
    #pragma unroll
    for (int i = 0; i < 5; ++i) {
        float2 v = *(const float2*)(ps + 2 * i);
        f[2 * i] = v.x; f[2 * i + 1] = v.y;
    }
    const float* pt = xt + (size_t)it * 5;
    #pragma unroll
    for (int i = 0; i < 5; ++i) f[10 + i] = pt[i];
    const float2* pe = (const float2*)(ea + (size_t)e * 10);
    #pragma unroll
    for (int i = 0; i < 5; ++i) { float2 v = pe[i]; f[15 + 2 * i] = v.x; f[16 + 2 * i] = v.y; }
    float h[10];
    #pragma unroll
    for (int j = 0; j < 10; ++j) h[j] = sUp[ib * 12 + j];
    #pragma unroll
    for (int k = 0; k < 25; ++k) {
        const float fk = f[k];
        #pragma unroll
        for (int j = 0; j < 10; ++j) h[j] += fk * W1[k * 10 + j];
    }
    #pragma unroll
    for (int j = 0; j < 10; ++j) h[j] = (h[j] >= 0.f) ? h[j] : 0.1f * h[j];
    float o[10];
    #pragma unroll
    for (int j = 0; j < 10; ++j) o[j] = b2[j];
    #pragma unroll
    for (int k = 0; k < 10; ++k) {
        const float hk = h[k];
        #pragma unroll
        for (int j = 0; j < 10; ++j) o[j] += hk * W2[k * 10 + j];
    }
    float2* po = (float2*)(out + (size_t)e * 10);
    #pragma unroll
    for (int i = 0; i < 5; ++i) { float2 v; v.x = o[2 * i]; v.y = o[2 * i + 1]; po[i] = v; }
}

extern "C" void kernel_launch(void* const* d_in, const int* in_sizes, int n_in,
                              void* d_out, int out_size, void* d_ws, size_t ws_size,
                              hipStream_t stream) {
    const float* x_s      = (const float*)d_in[0];
    const float* x_t      = (const float*)d_in[1];
    const int*   ei       = (const int*)d_in[2];    // (2, E) flat: [src | tgt]
    const float* edge_att = (const float*)d_in[3];
    const float* u        = (const float*)d_in[4];
    const int*   batch_e  = (const int*)d_in[5];
    const float* W1       = (const float*)d_in[6];
    const float* b1       = (const float*)d_in[7];
    const float* W2       = (const float*)d_in[8];
    const float* b2       = (const float*)d_in[9];
    float* out = (float*)d_out;

    const int E   = in_sizes[5];
    const int N_S = in_sizes[0] / 10;
    const int N_T = in_sizes[1] / 5;

    const size_t need = (size_t)N_S * sizeof(Row24) + (size_t)N_T * sizeof(uint4);
    if (ws_size >= need) {
        Row24* As = (Row24*)d_ws;
        uint4* Xt = (uint4*)((char*)d_ws + (size_t)N_S * sizeof(Row24));
        prep_as<<<(N_S + 255) / 256, 256, 0, stream>>>(x_s, W1, As, N_S);
        prep_xt<<<(N_T + 255) / 256, 256, 0, stream>>>(x_t, Xt, N_T);
        const int ntiles = (E + 255) / 256;
        const int blocks = (ntiles < 1792) ? ntiles : 1792;   // 7 persistent blocks/CU
        edge_mlp_dbuf<<<blocks, 256, 0, stream>>>(
            As, Xt, ei, ei + E, edge_att, u, batch_e,
            W1, b1, W2, b2, out, E, ntiles);
    } else {
        const int blocks = (E + 255) / 256;
        edge_mlp_raw<<<blocks, 256, 0, stream>>>(
            x_s, x_t, ei, ei + E, edge_att, u, batch_e,
            W1, b1, W2, b2, out, E);
    }
}